// Round 13
// baseline (71.194 us; speedup 1.0000x reference)
//
#include <hip/hip_runtime.h>
#include <hip/hip_bf16.h>

#define EMBED 256
#define LL 6   // layers

typedef __attribute__((ext_vector_type(8))) __bf16 bf16x8;
typedef __attribute__((ext_vector_type(4))) float f32x4;

// sigmoid(x) > 0.05  <=>  x > -ln(19)
#define SEL_THR (-2.9444389791664403f)
#define MAXPT4 32   // supports n up to 32768 elems at 256 threads

// ================= K1: block 0 = calib+select+bvec; blocks 1..32 = W prep ===
// 256 threads/block: select register cache v[32] (128 VGPR) fits WITHOUT spill.
__global__ __launch_bounds__(256, 1) void k_prep(
        const float* __restrict__ cls, int n,
        const float* __restrict__ rt,
        const float* __restrict__ W0, const float* __restrict__ W1,
        const float* __restrict__ b0, const float* __restrict__ b1,
        float* __restrict__ calib,
        int* __restrict__ bbox, int* __restrict__ cnt,
        __bf16* __restrict__ Wt0, __bf16* __restrict__ Wt1,
        float* __restrict__ bvec0, float* __restrict__ bvec1) {
    int tid = threadIdx.x;

    if (blockIdx.x != 0) {
        // ---------- W transpose -> bf16, 64x64 tile, 256 threads ----------
        int idx0 = blockIdx.x - 1;
        int which = idx0 >> 4;
        int t = idx0 & 15;
        int k0 = (t >> 2) * 64, c0 = (t & 3) * 64;
        const float* W = which ? W1 : W0;
        __bf16* Wt     = which ? Wt1 : Wt0;
        __shared__ float T[64][65];
#pragma unroll
        for (int i = 0; i < 16; ++i) {
            int idx = i * 256 + tid;
            int kk = idx >> 6, cc = idx & 63;
            T[kk][cc] = W[(size_t)(k0 + kk) * EMBED + c0 + cc];
        }
        __syncthreads();
#pragma unroll
        for (int i = 0; i < 16; ++i) {
            int idx = i * 256 + tid;
            int cc = idx >> 6, kk = idx & 63;
            Wt[(size_t)(c0 + cc) * EMBED + k0 + kk] = (__bf16)T[kk][cc];
        }
        return;
    }

    // ---------- block 0: calib (thread 0), select scan, bvec ----------
    __shared__ int warpCnt[4];
    __shared__ float s_calib[16];
    int wid = tid >> 6, lane = tid & 63;

    if (tid == 0) {
        double a[4][8];
        for (int i = 0; i < 4; ++i)
            for (int j = 0; j < 4; ++j) {
                a[i][j]     = (double)rt[j * 4 + i];
                a[i][4 + j] = (i == j) ? 1.0 : 0.0;
            }
        for (int c = 0; c < 4; ++c) {
            int p = c; double best = fabs(a[c][c]);
            for (int r = c + 1; r < 4; ++r) { double v = fabs(a[r][c]); if (v > best) { best = v; p = r; } }
            if (p != c) for (int j = 0; j < 8; ++j) { double t2 = a[c][j]; a[c][j] = a[p][j]; a[p][j] = t2; }
            double inv = 1.0 / a[c][c];
            for (int j = 0; j < 8; ++j) a[c][j] *= inv;
            for (int r = 0; r < 4; ++r) if (r != c) {
                double f = a[r][c];
                for (int j = 0; j < 8; ++j) a[r][j] -= f * a[c][j];
            }
        }
        for (int i = 0; i < 4; ++i)
            for (int j = 0; j < 4; ++j) {
                float v = (float)a[i][4 + j];
                calib[i * 4 + j] = v;
                s_calib[i * 4 + j] = v;
            }
    }

    int PT = ((n + 255) / 256 + 3) & ~3;   // elems/thread, x4 (96 for n=24576)
    int PT4 = PT >> 2;                      // <= MAXPT4
    int start = tid * PT;

    float4 v[MAXPT4];
#pragma unroll
    for (int j4 = 0; j4 < MAXPT4; ++j4) {
        if (j4 < PT4) {
            int s = start + j4 * 4;
            if (s + 4 <= n) {
                v[j4] = *(const float4*)&cls[s];
            } else {
                float4 t2; t2.x = t2.y = t2.z = t2.w = -1e30f;
                if (s + 0 < n) t2.x = cls[s + 0];
                if (s + 1 < n) t2.y = cls[s + 1];
                if (s + 2 < n) t2.z = cls[s + 2];
                if (s + 3 < n) t2.w = cls[s + 3];
                v[j4] = t2;
            }
        }
    }
    int c = 0;
#pragma unroll
    for (int j4 = 0; j4 < MAXPT4; ++j4) {
        if (j4 < PT4) {
            c += (v[j4].x > SEL_THR) + (v[j4].y > SEL_THR) +
                 (v[j4].z > SEL_THR) + (v[j4].w > SEL_THR);
        }
    }
    int incl = c;
#pragma unroll
    for (int off = 1; off < 64; off <<= 1) {
        int u = __shfl_up(incl, off, 64);
        if (lane >= off) incl += u;
    }
    if (lane == 63) warpCnt[wid] = incl;
    __syncthreads();   // warpCnt + s_calib ready

    int base = 0;
    for (int w2 = 0; w2 < wid; ++w2) base += warpCnt[w2];
    int pos = base + incl - c;
#pragma unroll
    for (int j4 = 0; j4 < MAXPT4; ++j4) {
        if (j4 < PT4) {
            int s = start + j4 * 4;
            if (s + 0 < n && v[j4].x > SEL_THR) bbox[pos++] = (s + 0) / 3;
            if (s + 1 < n && v[j4].y > SEL_THR) bbox[pos++] = (s + 1) / 3;
            if (s + 2 < n && v[j4].z > SEL_THR) bbox[pos++] = (s + 2) / 3;
            if (s + 3 < n && v[j4].w > SEL_THR) bbox[pos++] = (s + 3) / 3;
        }
    }
    if (tid == 0) {
        int tot = 0;
        for (int w2 = 0; w2 < 4; ++w2) tot += warpCnt[w2];
        *cnt = tot;
    }

    // bvec: 256 threads loop over which=0,1
#pragma unroll
    for (int which = 0; which < 2; ++which) {
        const float* W = which ? W1 : W0;
        const float* b = which ? b1 : b0;
        float* o       = which ? bvec1 : bvec0;
        float s = b[tid];
#pragma unroll
        for (int u = 0; u < 9; ++u) {
            float r = s_calib[(u / 3) * 4 + (u % 3)];
            s += r * W[(EMBED + u) * EMBED + tid];
        }
        o[tid] = s;
    }
}

// ================= K2: gather-GEMM standalone (R3/R6/R12-proven) ============
__device__ __forceinline__ bf16x8 cvt8(float4 f0, float4 f1) {
    bf16x8 r;
    r[0] = (__bf16)f0.x; r[1] = (__bf16)f0.y; r[2] = (__bf16)f0.z; r[3] = (__bf16)f0.w;
    r[4] = (__bf16)f1.x; r[5] = (__bf16)f1.y; r[6] = (__bf16)f1.z; r[7] = (__bf16)f1.w;
    return r;
}

__global__ __launch_bounds__(256, 4) void k_gemm(
        const float* __restrict__ q0, const float* __restrict__ q1,
        const int* __restrict__ bbox,
        const __bf16* __restrict__ Wt0, const __bf16* __restrict__ Wt1,
        const float* __restrict__ bvec0, const float* __restrict__ bvec1,
        float* __restrict__ out, int NI, int K, int off0, int off1) {
    int g = blockIdx.y;
    const float* q    = g ? q1 : q0;
    const __bf16* Wt  = g ? Wt1 : Wt0;
    const float* bvec = g ? bvec1 : bvec0;
    int out_off       = g ? off1 : off0;

    int tid  = threadIdx.x;
    int w    = tid >> 6;
    int lane = tid & 63;
    int lo16 = lane & 15;
    int kg   = lane >> 4;
    int r0 = blockIdx.x * 64;

    const float* aptr[4];
#pragma unroll
    for (int t = 0; t < 4; ++t) {
        int row = r0 + 16 * t + lo16;
        int rc = min(row, K - 1);
        int box = bbox[rc]; box = max(0, min(box, NI - 1));
        aptr[t] = q + (size_t)box * EMBED + kg * 8;
    }
    const __bf16* bptr[4];
#pragma unroll
    for (int t = 0; t < 4; ++t) {
        int col = w * 64 + 16 * t + lo16;
        bptr[t] = Wt + (size_t)col * EMBED + kg * 8;
    }

    f32x4 acc[4][4];
#pragma unroll
    for (int ct = 0; ct < 4; ++ct) {
        float bv = bvec[w * 64 + 16 * ct + lo16];
#pragma unroll
        for (int rt = 0; rt < 4; ++rt) {
            acc[rt][ct][0] = bv; acc[rt][ct][1] = bv; acc[rt][ct][2] = bv; acc[rt][ct][3] = bv;
        }
    }
    for (int s = 0; s < 8; ++s) {
        bf16x8 a[4], b[4];
#pragma unroll
        for (int t = 0; t < 4; ++t) {
            float4 f0 = *(const float4*)(aptr[t] + s * 32);
            float4 f1 = *(const float4*)(aptr[t] + s * 32 + 4);
            a[t] = cvt8(f0, f1);
            b[t] = *(const bf16x8*)(bptr[t] + s * 32);
        }
#pragma unroll
        for (int rt = 0; rt < 4; ++rt)
#pragma unroll
            for (int ct = 0; ct < 4; ++ct)
                acc[rt][ct] = __builtin_amdgcn_mfma_f32_16x16x32_bf16(a[rt], b[ct], acc[rt][ct], 0, 0, 0);
    }
#pragma unroll
    for (int rt = 0; rt < 4; ++rt) {
#pragma unroll
        for (int reg = 0; reg < 4; ++reg) {
            int row = r0 + 16 * rt + kg * 4 + reg;
            if (row < K) {
#pragma unroll
                for (int ct = 0; ct < 4; ++ct) {
                    int col = w * 64 + 16 * ct + lo16;
                    out[out_off + (size_t)row * EMBED + col] = acc[rt][ct][reg];
                }
            }
        }
    }
}

// ================= K3: m13-shaped streams, job = blockIdx.y =================
struct SJob { const float* src; int n4; int dstOff; int perLay4; int layStride; };
struct PlanS {
    SJob cj[5];                          // q, qp, cls, coord, ref
    const float* icls; const float* icoord; const float* iref;
    int dcls, dcoord, dref;
    int K, NI, NV, N;
};

__device__ __forceinline__ float inv_sig(float v) {
    v = fminf(fmaxf(v, 0.0f), 1.0f);
    float x1 = fmaxf(v, 1e-5f);
    float x2 = fmaxf(1.0f - v, 1e-5f);
    return logf(x1 / x2);
}

__global__ __launch_bounds__(256) void k_stream(PlanS P, const int* __restrict__ bbox,
                                                const float* __restrict__ calib,
                                                float* __restrict__ out) {
    int y = blockIdx.y;
    int tid = threadIdx.x;

    if (y < 5) {   // ---- plain grid-stride float4 copy (m13 shape) ----
        SJob J = P.cj[y];
        int stride = gridDim.x * 256;
        if (J.layStride == 0) {
            for (int i4 = blockIdx.x * 256 + tid; i4 < J.n4; i4 += stride) {
                float4 v = *(const float4*)&J.src[(size_t)i4 * 4];
                *(float4*)&out[(size_t)J.dstOff + (size_t)i4 * 4] = v;
            }
        } else {
            for (int i4 = blockIdx.x * 256 + tid; i4 < J.n4; i4 += stride) {
                int l = i4 / J.perLay4;
                int r = i4 - l * J.perLay4;
                float4 v = *(const float4*)&J.src[(size_t)i4 * 4];
                *(float4*)&out[(size_t)J.dstOff + (size_t)l * J.layStride + (size_t)r * 4] = v;
            }
        }
        return;
    }

    int stride = gridDim.x * 256;
    for (int k = blockIdx.x * 256 + tid; k < P.K; k += stride) {
        int box = bbox[k]; box = max(0, min(box, P.NI - 1));
        if (y == 5) {                  // ---- inf classes gather ----
#pragma unroll
            for (int l = 0; l < LL; ++l) {
                const float* s = P.icls + ((size_t)l * P.NI + box) * 3;
                size_t d = (size_t)P.dcls + ((size_t)l * P.N + P.NV) * 3 + (size_t)k * 3;
                out[d + 0] = s[0]; out[d + 1] = s[1]; out[d + 2] = s[2];
            }
        } else if (y == 6) {           // ---- inf coords gather+transform ----
            float c00 = calib[0], c01 = calib[1], c03 = calib[3];
            float c10 = calib[4], c11 = calib[5], c13 = calib[7];
            float zx = calib[2] * -5.0f, zy = calib[6] * -5.0f;
#pragma unroll
            for (int l = 0; l < LL; ++l) {
                float4 s = *(const float4*)&P.icoord[((size_t)l * P.NI + box) * 4];
                float X = s.x * 102.4f;
                float Y = s.y * 102.4f - 51.2f;
                float tx = c00 * X + c01 * Y + zx + c03;
                float ty = c10 * X + c11 * Y + zy + c13;
                float4 v = make_float4((tx + 51.2f) * (1.0f / 102.4f),
                                       (ty + 51.2f) * (1.0f / 102.4f), s.z, s.w);
                *(float4*)&out[(size_t)P.dcoord + ((size_t)l * P.N + P.NV + k) * 4] = v;
            }
        } else {                       // ---- inf reference ----
            float4 s = *(const float4*)&P.iref[(size_t)box * 4];
            float sx = 1.0f / (1.0f + expf(-s.x));
            float sy = 1.0f / (1.0f + expf(-s.y));
            float X = sx * 102.4f;
            float Y = sy * 102.4f - 51.2f;
            float tx = calib[0] * X + calib[1] * Y + calib[2] * -1.0f + calib[3];
            float ty = calib[4] * X + calib[5] * Y + calib[6] * -1.0f + calib[7];
            float4 v = make_float4(inv_sig((tx + 51.2f) * (1.0f / 102.4f)),
                                   inv_sig((ty + 51.2f) * (1.0f / 102.4f)), s.z, s.w);
            *(float4*)&out[(size_t)P.dref + ((size_t)P.NV + k) * 4] = v;
        }
    }
}

extern "C" void kernel_launch(void* const* d_in, const int* in_sizes, int n_in,
                              void* d_out, int out_size, void* d_ws, size_t ws_size,
                              hipStream_t stream) {
    const float* inf_cls   = (const float*)d_in[0];
    const float* inf_coord = (const float*)d_in[1];
    const float* inf_q     = (const float*)d_in[2];
    const float* inf_qp    = (const float*)d_in[3];
    const float* inf_ref   = (const float*)d_in[4];
    const float* veh_cls   = (const float*)d_in[5];
    const float* veh_coord = (const float*)d_in[6];
    const float* veh_q     = (const float*)d_in[7];
    const float* veh_qp    = (const float*)d_in[8];
    const float* veh_ref   = (const float*)d_in[9];
    const float* rt        = (const float*)d_in[10];
    const float* W0        = (const float*)d_in[11];
    const float* b0        = (const float*)d_in[12];
    const float* W1        = (const float*)d_in[13];
    const float* b1        = (const float*)d_in[14];
    float* out = (float*)d_out;

    int NI = in_sizes[0] / (LL * 3);
    int NV = in_sizes[5] / (LL * 3);
    int N  = out_size / 558;
    int K  = N - NV;

    int off_cls   = 0;
    int off_coord = LL * N * 3;
    int off_q     = off_coord + LL * N * 4;
    int off_qp    = off_q + N * EMBED;
    int off_ref   = off_qp + N * EMBED;

    char* ws = (char*)d_ws;
    float* calib = (float*)(ws);
    float* bvec0 = (float*)(ws + 128);
    float* bvec1 = (float*)(ws + 1152);
    int*   cnt   = (int*)(ws + 2176);
    int*   bbox  = (int*)(ws + 2304);
    __bf16* Wt0  = (__bf16*)(ws + 131072);
    __bf16* Wt1  = (__bf16*)(ws + 262144);

    // K1: select/calib/bvec + W prep (256-thread, spill-free)
    hipLaunchKernelGGL(k_prep, dim3(33), dim3(256), 0, stream,
                       inf_cls + (size_t)(LL - 1) * NI * 3, NI * 3, rt,
                       W0, W1, b0, b1, calib, bbox, cnt, Wt0, Wt1, bvec0, bvec1);

    // K2: gather-GEMM alone
    if (K > 0) {
        hipLaunchKernelGGL(k_gemm, dim3((K + 63) / 64, 2), dim3(256), 0, stream,
                           inf_q, inf_qp, bbox, Wt0, Wt1, bvec0, bvec1,
                           out, NI, K, off_q + NV * EMBED, off_qp + NV * EMBED);
    }

    // K3: m13-shaped streams
    {
        PlanS P;
        P.cj[0] = { veh_q,     NV * EMBED / 4,  off_q,     NV * EMBED / 4, 0 };
        P.cj[1] = { veh_qp,    NV * EMBED / 4,  off_qp,    NV * EMBED / 4, 0 };
        P.cj[2] = { veh_cls,   LL * NV * 3 / 4, off_cls,   NV * 3 / 4,     N * 3 };
        P.cj[3] = { veh_coord, LL * NV * 4 / 4, off_coord, NV * 4 / 4,     N * 4 };
        P.cj[4] = { veh_ref,   NV * 4 / 4,      off_ref,   NV * 4 / 4,     0 };
        P.icls = inf_cls; P.icoord = inf_coord; P.iref = inf_ref;
        P.dcls = off_cls; P.dcoord = off_coord; P.dref = off_ref;
        P.K = K; P.NI = NI; P.NV = NV; P.N = N;
        hipLaunchKernelGGL(k_stream, dim3(1024, 8), dim3(256), 0, stream,
                           P, bbox, calib, out);
    }
}